// Round 1
// baseline (423.697 us; speedup 1.0000x reference)
//
#include <hip/hip_runtime.h>
#include <hip/hip_bf16.h>
#include <stdint.h>

#define BATCH 16
#define NDIM  4096   // h*w
#define CDIM  512
#define HID   128
#define QKV_O 384
static constexpr float SCALE = 0.17677669529663687f; // 1/sqrt(32)
static constexpr float EPS = 1e-5f;

typedef __attribute__((ext_vector_type(8))) short s16x8;
typedef __attribute__((ext_vector_type(4))) short s16x4;
typedef __attribute__((ext_vector_type(4))) float f32x4;

#define DEV static __device__ __forceinline__

DEV float b2f(unsigned short u) {
  union { unsigned int i; float f; } c; c.i = ((unsigned int)u) << 16; return c.f;
}
DEV unsigned short f2bf(float f) {
  union { float f; unsigned int i; } c; c.f = f;
  unsigned int u = c.i;
  u += 0x7FFF + ((u >> 16) & 1);   // RNE
  return (unsigned short)(u >> 16);
}
DEV void gload_lds16(const void* g, void* l) {
  __builtin_amdgcn_global_load_lds((const __attribute__((address_space(1))) void*)g,
                                   (__attribute__((address_space(3))) void*)l, 16, 0, 0);
}

// ---------------- W_qkv fp32 -> bf16 ----------------
__global__ __launch_bounds__(256) void k_convw(const float* __restrict__ W,
                                               unsigned short* __restrict__ Wb) {
  int i = (blockIdx.x * 256 + threadIdx.x) * 8;
  float4 a = *(const float4*)(W + i);
  float4 b = *(const float4*)(W + i + 4);
  s16x8 o;
  o[0] = (short)f2bf(a.x); o[1] = (short)f2bf(a.y);
  o[2] = (short)f2bf(a.z); o[3] = (short)f2bf(a.w);
  o[4] = (short)f2bf(b.x); o[5] = (short)f2bf(b.y);
  o[6] = (short)f2bf(b.z); o[7] = (short)f2bf(b.w);
  *(s16x8*)(Wb + i) = o;
}

// ---------------- x [b][c][n] fp32 -> xT [b][n][c] bf16 ----------------
__global__ __launch_bounds__(256) void k_transpose(const float* __restrict__ x,
                                                   unsigned short* __restrict__ xT) {
  __shared__ float tile[64][65];
  int b = blockIdx.z, c0 = blockIdx.y * 64, n0 = blockIdx.x * 64;
  int t = threadIdx.x;
  int tr = t >> 6;   // wave id 0..3 (uniform per wave)
  int tc = t & 63;   // lane
  const float* src = x + ((size_t)b * CDIM + c0) * NDIM + n0;
  #pragma unroll
  for (int i = 0; i < 16; ++i) {
    int r = tr + i * 4;
    tile[r][tc] = src[(size_t)r * NDIM + tc];
  }
  __syncthreads();
  unsigned short* dst = xT + ((size_t)b * NDIM + n0) * CDIM + c0;
  #pragma unroll
  for (int i = 0; i < 16; ++i) {
    int r = tr + i * 4;  // output n-row
    dst[(size_t)r * CDIM + tc] = f2bf(tile[tc][r]);
  }
}

// ---------------- 128x128-tile bf16 MFMA GEMM (A [M][K], Bt [N][K], both K-contig) ----
// FINAL=false: C bf16 [b][384][4096].  FINAL=true: C fp32 d_out [b][512][4096] + bias + stats.
template<int KD, bool FINAL>
__global__ __launch_bounds__(256) void k_gemm(const unsigned short* __restrict__ A, size_t aStride,
                                              const unsigned short* __restrict__ Bt,
                                              void* __restrict__ Cout,
                                              const float* __restrict__ bias,
                                              float* __restrict__ stats) {
  __shared__ unsigned short As[128 * 32];
  __shared__ unsigned short Bs[128 * 32];
  const int b = blockIdx.z;
  const int m0 = blockIdx.y * 128, n0 = blockIdx.x * 128;
  const int t = threadIdx.x, lane = t & 63, wid = t >> 6;
  const int wr = wid >> 1, wc = wid & 1;
  const int l15 = lane & 15, l4 = lane >> 4;

  const unsigned short* Ab = A + aStride * b;
  const unsigned short* Bb = Bt + (size_t)b * NDIM * KD;

  f32x4 acc[4][4] = {};

  for (int k0 = 0; k0 < KD; k0 += 32) {
    if (k0) __syncthreads();
    #pragma unroll
    for (int c = 0; c < 2; ++c) {
      int chunk = c * 4 + wid;
      int off = chunk * 1024 + lane * 16;  // byte offset into 8 KB tile
      int row = off >> 6;                  // 64 B per tile row (32 bf16)
      int colB = off & 63;
      gload_lds16((const char*)(Ab + (size_t)(m0 + row) * KD + k0) + colB,
                  (char*)As + chunk * 1024);
      gload_lds16((const char*)(Bb + (size_t)(n0 + row) * KD + k0) + colB,
                  (char*)Bs + chunk * 1024);
    }
    __syncthreads();
    s16x8 af[4], bfr[4];
    #pragma unroll
    for (int i = 0; i < 4; ++i) {
      int r = wr * 64 + i * 16 + l15;
      af[i] = *(const s16x8*)&As[r * 32 + l4 * 8];
      int cN = wc * 64 + i * 16 + l15;
      bfr[i] = *(const s16x8*)&Bs[cN * 32 + l4 * 8];
    }
    #pragma unroll
    for (int mi = 0; mi < 4; ++mi)
      #pragma unroll
      for (int ni = 0; ni < 4; ++ni)
        acc[mi][ni] = __builtin_amdgcn_mfma_f32_16x16x32_bf16(af[mi], bfr[ni], acc[mi][ni], 0, 0, 0);
  }

  if constexpr (!FINAL) {
    unsigned short* C = (unsigned short*)Cout + (size_t)b * QKV_O * NDIM;
    #pragma unroll
    for (int mi = 0; mi < 4; ++mi) {
      #pragma unroll
      for (int r = 0; r < 4; ++r) {
        int row = m0 + wr * 64 + mi * 16 + l4 * 4 + r;
        unsigned short* cp = C + (size_t)row * NDIM + n0 + wc * 64 + l15;
        #pragma unroll
        for (int ni = 0; ni < 4; ++ni)
          cp[ni * 16] = f2bf(acc[mi][ni][r]);
      }
    }
  } else {
    float* C = (float*)Cout + (size_t)b * CDIM * NDIM;
    float s = 0.f, s2 = 0.f;
    #pragma unroll
    for (int mi = 0; mi < 4; ++mi) {
      #pragma unroll
      for (int r = 0; r < 4; ++r) {
        int row = m0 + wr * 64 + mi * 16 + l4 * 4 + r;
        float bv = bias[row];
        float* cp = C + (size_t)row * NDIM + n0 + wc * 64 + l15;
        #pragma unroll
        for (int ni = 0; ni < 4; ++ni) {
          float v = acc[mi][ni][r] + bv;
          cp[ni * 16] = v;
          s += v; s2 += v * v;
        }
      }
    }
    #pragma unroll
    for (int o = 32; o > 0; o >>= 1) {
      s  += __shfl_down(s, o, 64);
      s2 += __shfl_down(s2, o, 64);
    }
    __syncthreads();
    float* red = (float*)As;
    if (lane == 0) { red[wid * 2] = s; red[wid * 2 + 1] = s2; }
    __syncthreads();
    if (t == 0) {
      float ts = red[0] + red[2] + red[4] + red[6];
      float t2 = red[1] + red[3] + red[5] + red[7];
      atomicAdd(&stats[b * 2], ts);
      atomicAdd(&stats[b * 2 + 1], t2);
    }
  }
}

// ---------------- k-softmax stats: per (b,h,d) max and Z over n ----------------
__global__ __launch_bounds__(256) void k_kstats(const unsigned short* __restrict__ qkv,
                                                float* __restrict__ kmax, float* __restrict__ kZ) {
  int bhd = blockIdx.x;            // b*128 + h*32 + d
  int b = bhd >> 7, hd = bhd & 127;
  const unsigned short* krow = qkv + ((size_t)b * QKV_O + HID + hd) * NDIM;
  int t = threadIdx.x, lane = t & 63, wid = t >> 6;
  const s16x8* kp = (const s16x8*)(krow + t * 16);
  s16x8 r0 = kp[0], r1 = kp[1];
  float v[16];
  #pragma unroll
  for (int j = 0; j < 8; ++j) { v[j] = b2f((unsigned short)r0[j]); v[8 + j] = b2f((unsigned short)r1[j]); }
  float m = v[0];
  #pragma unroll
  for (int j = 1; j < 16; ++j) m = fmaxf(m, v[j]);
  #pragma unroll
  for (int o = 32; o > 0; o >>= 1) m = fmaxf(m, __shfl_xor(m, o, 64));
  __shared__ float red[8];
  if (lane == 0) red[wid] = m;
  __syncthreads();
  m = fmaxf(fmaxf(red[0], red[1]), fmaxf(red[2], red[3]));
  float s = 0.f;
  #pragma unroll
  for (int j = 0; j < 16; ++j) s += __expf(v[j] - m);
  #pragma unroll
  for (int o = 32; o > 0; o >>= 1) s += __shfl_xor(s, o, 64);
  if (lane == 0) red[4 + wid] = s;
  __syncthreads();
  if (t == 0) { kmax[bhd] = m; kZ[bhd] = red[4] + red[5] + red[6] + red[7]; }
}

// ---------------- ctx_raw[b][h][d][e] += sum_n exp(k-max)*v ----------------
__global__ __launch_bounds__(256) void k_ctx(const unsigned short* __restrict__ qkv,
                                             const float* __restrict__ kmax,
                                             float* __restrict__ ctx) {
  __shared__ unsigned short kx[32 * 264];   // row pitch 264 shorts = 528 B (16-B aligned)
  __shared__ unsigned short vx[32 * 264];
  int nc = blockIdx.x, h = blockIdx.y, b = blockIdx.z;
  int t = threadIdx.x;
  int row = t >> 3, cb = (t & 7) * 32;
  int n0 = nc * 256;
  const unsigned short* kg = qkv + ((size_t)b * QKV_O + HID + h * 32 + row) * NDIM + n0 + cb;
  const unsigned short* vg = qkv + ((size_t)b * QKV_O + 2 * HID + h * 32 + row) * NDIM + n0 + cb;
  unsigned short* kl = kx + row * 264 + cb;
  unsigned short* vl = vx + row * 264 + cb;
  #pragma unroll
  for (int j = 0; j < 4; ++j) {
    *(s16x8*)(kl + j * 8) = *(const s16x8*)(kg + j * 8);
    *(s16x8*)(vl + j * 8) = *(const s16x8*)(vg + j * 8);
  }
  // p = exp(k - kmax) in place (thread rewrites only its own staged slots)
  float km = kmax[b * 128 + h * 32 + row];
  #pragma unroll
  for (int j = 0; j < 32; ++j) kl[j] = (unsigned short)f2bf(__expf(b2f(kl[j]) - km));
  __syncthreads();
  int d = t >> 3, eq = t & 7;
  const unsigned short* pr = kx + d * 264;
  const unsigned short* v0 = vx + (eq * 4 + 0) * 264;
  const unsigned short* v1 = vx + (eq * 4 + 1) * 264;
  const unsigned short* v2 = vx + (eq * 4 + 2) * 264;
  const unsigned short* v3 = vx + (eq * 4 + 3) * 264;
  float a0 = 0, a1 = 0, a2 = 0, a3 = 0;
  for (int n4 = 0; n4 < 64; ++n4) {
    s16x4 p4 = *(const s16x4*)(pr + n4 * 4);
    s16x4 w0 = *(const s16x4*)(v0 + n4 * 4);
    s16x4 w1 = *(const s16x4*)(v1 + n4 * 4);
    s16x4 w2 = *(const s16x4*)(v2 + n4 * 4);
    s16x4 w3 = *(const s16x4*)(v3 + n4 * 4);
    #pragma unroll
    for (int j = 0; j < 4; ++j) {
      float p = b2f((unsigned short)p4[j]);
      a0 += p * b2f((unsigned short)w0[j]);
      a1 += p * b2f((unsigned short)w1[j]);
      a2 += p * b2f((unsigned short)w2[j]);
      a3 += p * b2f((unsigned short)w3[j]);
    }
  }
  float* cp = ctx + (((size_t)b * 4 + h) * 32 + d) * 32 + eq * 4;
  atomicAdd(cp + 0, a0); atomicAdd(cp + 1, a1);
  atomicAdd(cp + 2, a2); atomicAdd(cp + 3, a3);
}

// ---------------- M_b[co][hd] = sum_e W_out[co][h*32+e] * ctx[h][d][e]*scale/Z ----------------
__global__ __launch_bounds__(256) void k_mb(const float* __restrict__ Wout,
                                            const float* __restrict__ ctx,
                                            const float* __restrict__ kZ,
                                            unsigned short* __restrict__ Mb) {
  __shared__ float cs[4096];
  int b = blockIdx.y, co0 = blockIdx.x * 32;
  int t = threadIdx.x;
  for (int i = t; i < 4096; i += 256) {
    int h = i >> 10, d = (i >> 5) & 31;
    cs[i] = ctx[(size_t)b * 4096 + i] * (SCALE / kZ[b * 128 + h * 32 + d]);
  }
  __syncthreads();
  int co = co0 + (t >> 3);
  int hd0 = (t & 7) * 16;
  const float* wr = Wout + (size_t)co * HID;
  unsigned short* out = Mb + ((size_t)b * CDIM + co) * HID;
  for (int u = 0; u < 16; ++u) {
    int hd = hd0 + u;
    int h = hd >> 5, d = hd & 31;
    const float* ch = cs + h * 1024 + d * 32;
    const float* wh = wr + h * 32;
    float acc = 0.f;
    #pragma unroll
    for (int e = 0; e < 32; ++e) acc += wh[e] * ch[e];
    out[hd] = f2bf(acc);
  }
}

// ---------------- qsmT[b][n][128] = softmax over d of q (per head), bf16 ----------------
__global__ __launch_bounds__(256) void k_qsm(const unsigned short* __restrict__ qkv,
                                             unsigned short* __restrict__ qsmT) {
  int b = blockIdx.y;
  int n = blockIdx.x * 256 + threadIdx.x;
  const unsigned short* qb = qkv + (size_t)b * QKV_O * NDIM + n;
  unsigned short* o = qsmT + ((size_t)b * NDIM + n) * HID;
  #pragma unroll
  for (int h = 0; h < 4; ++h) {
    float v[32];
    float m = -1e30f;
    #pragma unroll
    for (int d = 0; d < 32; ++d) { v[d] = b2f(qb[(size_t)(h * 32 + d) * NDIM]); m = fmaxf(m, v[d]); }
    float s = 0.f;
    #pragma unroll
    for (int d = 0; d < 32; ++d) { v[d] = __expf(v[d] - m); s += v[d]; }
    float inv = 1.0f / s;
    s16x8 pack[4];
    #pragma unroll
    for (int d = 0; d < 32; ++d) pack[d >> 3][d & 7] = (short)f2bf(v[d] * inv);
    #pragma unroll
    for (int j = 0; j < 4; ++j) *(s16x8*)(o + h * 32 + j * 8) = pack[j];
  }
}

// ---------------- GroupNorm finalize in place ----------------
__global__ __launch_bounds__(256) void k_gn(float* __restrict__ out,
                                            const float* __restrict__ stats,
                                            const float* __restrict__ gamma,
                                            const float* __restrict__ beta) {
  int b = blockIdx.y;
  constexpr float invN = 1.0f / ((float)CDIM * (float)NDIM);
  float mean = stats[b * 2] * invN;
  float var = stats[b * 2 + 1] * invN - mean * mean;
  float rstd = rsqrtf(var + EPS);
  int i = blockIdx.x * 256 + threadIdx.x;
  size_t base = (size_t)b * CDIM * NDIM + (size_t)i * 8;
  int c = (i * 8) >> 12;
  float g = gamma[c] * rstd;
  float sh = beta[c] - mean * g;
  float4 x0 = *(float4*)(out + base);
  float4 x1 = *(float4*)(out + base + 4);
  x0.x = x0.x * g + sh; x0.y = x0.y * g + sh; x0.z = x0.z * g + sh; x0.w = x0.w * g + sh;
  x1.x = x1.x * g + sh; x1.y = x1.y * g + sh; x1.z = x1.z * g + sh; x1.w = x1.w * g + sh;
  *(float4*)(out + base) = x0;
  *(float4*)(out + base + 4) = x1;
}

extern "C" void kernel_launch(void* const* d_in, const int* in_sizes, int n_in,
                              void* d_out, int out_size, void* d_ws, size_t ws_size,
                              hipStream_t stream) {
  const float* x     = (const float*)d_in[0];
  const float* Wqkv  = (const float*)d_in[1];
  const float* Wout  = (const float*)d_in[2];
  const float* bout  = (const float*)d_in[3];
  const float* gamma = (const float*)d_in[4];
  const float* beta  = (const float*)d_in[5];
  char* ws = (char*)d_ws;
  // workspace layout (total ~130.6 MiB)
  unsigned short* xT   = (unsigned short*)(ws);               // 67108864 B
  unsigned short* qkv  = (unsigned short*)(ws + 67108864);    // 50331648 B
  unsigned short* qsmT = (unsigned short*)(ws + 117440512);   // 16777216 B
  unsigned short* Mb   = (unsigned short*)(ws + 134217728);   //  2097152 B
  unsigned short* Wqb  = (unsigned short*)(ws + 136314880);   //   393216 B
  float* kmax  = (float*)(ws + 136708096);                    //     8192 B
  float* kZ    = (float*)(ws + 136716288);                    //     8192 B
  float* ctx   = (float*)(ws + 136724480);                    //   262144 B
  float* stats = (float*)(ws + 136986624);                    //      128 B
  float* out = (float*)d_out;

  hipMemsetAsync(ws + 136724480, 0, 262144 + 128, stream);   // zero ctx + stats

  k_convw<<<96, 256, 0, stream>>>(Wqkv, Wqb);
  k_transpose<<<dim3(64, 8, 16), 256, 0, stream>>>(x, xT);
  k_gemm<512, false><<<dim3(32, 3, 16), 256, 0, stream>>>(Wqb, 0, xT, qkv, nullptr, nullptr);
  k_kstats<<<2048, 256, 0, stream>>>(qkv, kmax, kZ);
  k_ctx<<<dim3(16, 4, 16), 256, 0, stream>>>(qkv, kmax, ctx);
  k_mb<<<dim3(16, 16), 256, 0, stream>>>(Wout, ctx, kZ, Mb);
  k_qsm<<<dim3(16, 16), 256, 0, stream>>>(qkv, qsmT);
  k_gemm<128, true><<<dim3(32, 4, 16), 256, 0, stream>>>(Mb, (size_t)CDIM * HID, qsmT, out, bout, stats);
  k_gn<<<dim3(1024, 16), 256, 0, stream>>>(out, stats, gamma, beta);
}